// Round 3
// baseline (886.987 us; speedup 1.0000x reference)
//
#include <hip/hip_runtime.h>

#define N_NODES 12288
#define IN_F    256
#define OUT_F   64
#define KSPLIT  8
#define MT      64

typedef __attribute__((ext_vector_type(8))) short bf16x8;
typedef __attribute__((ext_vector_type(4))) float f32x4;
typedef __attribute__((ext_vector_type(4))) int   i32x4;

__device__ __forceinline__ unsigned short f2bf(float f) {
    union { float f; unsigned int i; } v; v.f = f;
    unsigned int x = v.i;
    unsigned int r = x + 0x7FFFu + ((x >> 16) & 1u);  // RNE
    return (unsigned short)(r >> 16);
}

// ---------------- kernel 1: hT[n][i] = bf16( (x @ W)[i][n] )  via MFMA
// W staged once per block into LDS (transposed, bf16); x converted in regs.
__global__ __launch_bounds__(256) void k_hT(const float* __restrict__ x,
                                            const float* __restrict__ W,
                                            unsigned short* __restrict__ hT) {
    __shared__ unsigned short WT[OUT_F][IN_F + 8];   // WT[n][k] = bf16(W[k][n]); stride 264 (16B-aligned rows)
    int tid = threadIdx.x;
    for (int idx = tid; idx < IN_F * OUT_F; idx += 256) {
        int k = idx >> 6, n = idx & 63;
        WT[n][k] = f2bf(W[idx]);
    }
    __syncthreads();

    int lane = tid & 63, wave = tid >> 6;
    int q = lane >> 4, ml = lane & 15;
    int i0 = blockIdx.x * MT;
    int row = i0 + 16 * wave + ml;
    const float* xr = x + (size_t)row * IN_F + 8 * q;

    f32x4 acc[4];
    #pragma unroll
    for (int nt = 0; nt < 4; ++nt) acc[nt] = (f32x4){0.f, 0.f, 0.f, 0.f};

    #pragma unroll
    for (int kk = 0; kk < IN_F; kk += 32) {
        float4 x0 = *(const float4*)(xr + kk);
        float4 x1 = *(const float4*)(xr + kk + 4);
        union { bf16x8 v; unsigned short u[8]; } A;
        A.u[0] = f2bf(x0.x); A.u[1] = f2bf(x0.y); A.u[2] = f2bf(x0.z); A.u[3] = f2bf(x0.w);
        A.u[4] = f2bf(x1.x); A.u[5] = f2bf(x1.y); A.u[6] = f2bf(x1.z); A.u[7] = f2bf(x1.w);
        #pragma unroll
        for (int nt = 0; nt < 4; ++nt) {
            bf16x8 bv = *(const bf16x8*)&WT[16 * nt + ml][kk + 8 * q];
            acc[nt] = __builtin_amdgcn_mfma_f32_16x16x32_bf16(A.v, bv, acc[nt], 0, 0, 0);
        }
    }

    // C layout: col(n)=16nt+ml, row(m)=i0+16w+4q+rr -> hT[n][m], 4 consecutive m => 8B store
    #pragma unroll
    for (int nt = 0; nt < 4; ++nt) {
        ushort4 o;
        o.x = f2bf(acc[nt][0]); o.y = f2bf(acc[nt][1]);
        o.z = f2bf(acc[nt][2]); o.w = f2bf(acc[nt][3]);
        *(ushort4*)&hT[(size_t)(16 * nt + ml) * N_NODES + i0 + 16 * wave + 4 * q] = o;
    }
}

// ---------------- kernel 2: barrier-free SpMM slice + degree rowsum
// Each lane loads its MFMA fragments straight from global: A from adj
// (nontemporal, 0/1 -> bf16 in regs), B from hT (L2/L3-resident, 1.5 MB).
__global__ __launch_bounds__(256) void k_spmm(const int* __restrict__ adj,
                                              const unsigned short* __restrict__ hT,
                                              float* __restrict__ s_part,
                                              int* __restrict__ deg_part) {
    int tid = threadIdx.x, lane = tid & 63, wave = tid >> 6;
    int q = lane >> 4, ml = lane & 15;
    int i0 = blockIdx.x * MT;
    int ks = blockIdx.y;
    const int KR = N_NODES / KSPLIT;                 // 1536
    int k0b = ks * KR;
    int row = i0 + 16 * wave + ml;                   // this lane's A row
    const int* ap = adj + (size_t)row * N_NODES + k0b + 8 * q;
    const unsigned short* bp = hT + (size_t)ml * N_NODES + k0b + 8 * q;

    f32x4 acc[4];
    #pragma unroll
    for (int nt = 0; nt < 4; ++nt) acc[nt] = (f32x4){0.f, 0.f, 0.f, 0.f};
    int degacc = 0;

    #pragma unroll 4
    for (int kk = 0; kk < KR; kk += 32) {
        i32x4 a0 = __builtin_nontemporal_load((const i32x4*)(ap + kk));
        i32x4 a1 = __builtin_nontemporal_load((const i32x4*)(ap + kk) + 1);
        degacc += a0.x + a0.y + a0.z + a0.w + a1.x + a1.y + a1.z + a1.w;
        union { bf16x8 v; unsigned short u[8]; } A;
        A.u[0] = a0.x ? 0x3F80 : 0; A.u[1] = a0.y ? 0x3F80 : 0;
        A.u[2] = a0.z ? 0x3F80 : 0; A.u[3] = a0.w ? 0x3F80 : 0;
        A.u[4] = a1.x ? 0x3F80 : 0; A.u[5] = a1.y ? 0x3F80 : 0;
        A.u[6] = a1.z ? 0x3F80 : 0; A.u[7] = a1.w ? 0x3F80 : 0;
        #pragma unroll
        for (int nt = 0; nt < 4; ++nt) {
            bf16x8 bv = *(const bf16x8*)(bp + (size_t)(16 * nt) * N_NODES + kk);
            acc[nt] = __builtin_amdgcn_mfma_f32_16x16x32_bf16(A.v, bv, acc[nt], 0, 0, 0);
        }
    }

    // epilogue: block owns its 64x64 region of slice ks (non-atomic)
    float* sp = s_part + (size_t)ks * ((size_t)N_NODES * OUT_F);
    #pragma unroll
    for (int nt = 0; nt < 4; ++nt) {
        #pragma unroll
        for (int rr = 0; rr < 4; ++rr) {
            int r = i0 + 16 * wave + 4 * q + rr;     // C layout: row = quad*4+reg
            int c = 16 * nt + ml;                    // col = lane&15
            sp[(size_t)r * OUT_F + c] = acc[nt][rr];
        }
    }

    // degree: lanes (ml, ml+16, ml+32, ml+48) share a row -> reduce over q
    degacc += __shfl_xor(degacc, 16, 64);
    degacc += __shfl_xor(degacc, 32, 64);
    if (lane < 16)
        deg_part[ks * N_NODES + row] = degacc;
}

// ---------------- kernel 3: out = elu( sum_p s_part / sum_p deg_part ), fp32
__global__ __launch_bounds__(256) void k_out(const float* __restrict__ s_part,
                                             const int* __restrict__ deg_part,
                                             float* __restrict__ out) {
    int idx = blockIdx.x * 256 + threadIdx.x;
    int i = idx >> 6;
    float s = 0.f; int deg = 0;
    #pragma unroll
    for (int p = 0; p < KSPLIT; ++p) {
        s   += s_part[(size_t)p * ((size_t)N_NODES * OUT_F) + idx];
        deg += deg_part[p * N_NODES + i];
    }
    float v = (deg > 0) ? (s / (float)deg) : 0.f;
    out[idx] = (v > 0.f) ? v : expm1f(v);
}

extern "C" void kernel_launch(void* const* d_in, const int* in_sizes, int n_in,
                              void* d_out, int out_size, void* d_ws, size_t ws_size,
                              hipStream_t stream) {
    const int*   adj = (const int*)d_in[0];
    const float* x   = (const float*)d_in[1];   // fp32
    const float* W   = (const float*)d_in[2];   // fp32
    // d_in[3] (a) provably cancels out of the output — unused.
    float* out = (float*)d_out;                 // fp32

    char* ws = (char*)d_ws;
    const size_t hT_bytes = (size_t)N_NODES * OUT_F * 2;                 // 1.5 MB
    const size_t sp_bytes = (size_t)KSPLIT * N_NODES * OUT_F * 4;        // 25.2 MB
    unsigned short* hT = (unsigned short*)ws;
    float* s_part      = (float*)(ws + hT_bytes);
    int*   deg_part    = (int*)(ws + hT_bytes + sp_bytes);
    // total ~27 MB of d_ws

    k_hT  <<<dim3(N_NODES / MT),          dim3(256), 0, stream>>>(x, W, hT);
    k_spmm<<<dim3(N_NODES / MT, KSPLIT),  dim3(256), 0, stream>>>(adj, hT, s_part, deg_part);
    k_out <<<dim3(N_NODES * OUT_F / 256), dim3(256), 0, stream>>>(s_part, deg_part, out);
}

// Round 4
// 815.252 us; speedup vs baseline: 1.0880x; 1.0880x over previous
//
#include <hip/hip_runtime.h>

#define N_NODES 12288
#define IN_F    256
#define OUT_F   64
#define KSPLIT  4
#define BK      64
#define MT      64

typedef __attribute__((ext_vector_type(8))) short bf16x8;
typedef __attribute__((ext_vector_type(4))) float f32x4;

__device__ __forceinline__ unsigned short f2bf(float f) {
    union { float f; unsigned int i; } v; v.f = f;
    unsigned int x = v.i;
    unsigned int r = x + 0x7FFFu + ((x >> 16) & 1u);  // RNE
    return (unsigned short)(r >> 16);
}

// ---------------- kernel 1: hT[n][i] = bf16( (x @ W)[i][n] )  via MFMA
// W staged once per block into LDS (transposed, bf16); x converted in regs.
__global__ __launch_bounds__(256) void k_hT(const float* __restrict__ x,
                                            const float* __restrict__ W,
                                            unsigned short* __restrict__ hT) {
    __shared__ unsigned short WT[OUT_F][IN_F + 8];   // WT[n][k] = bf16(W[k][n])
    int tid = threadIdx.x;
    for (int idx = tid; idx < IN_F * OUT_F; idx += 256) {
        int k = idx >> 6, n = idx & 63;
        WT[n][k] = f2bf(W[idx]);
    }
    __syncthreads();

    int lane = tid & 63, wave = tid >> 6;
    int q = lane >> 4, ml = lane & 15;
    int i0 = blockIdx.x * MT;
    int row = i0 + 16 * wave + ml;
    const float* xr = x + (size_t)row * IN_F + 8 * q;

    f32x4 acc[4];
    #pragma unroll
    for (int nt = 0; nt < 4; ++nt) acc[nt] = (f32x4){0.f, 0.f, 0.f, 0.f};

    #pragma unroll
    for (int kk = 0; kk < IN_F; kk += 32) {
        float4 x0 = *(const float4*)(xr + kk);
        float4 x1 = *(const float4*)(xr + kk + 4);
        union { bf16x8 v; unsigned short u[8]; } A;
        A.u[0] = f2bf(x0.x); A.u[1] = f2bf(x0.y); A.u[2] = f2bf(x0.z); A.u[3] = f2bf(x0.w);
        A.u[4] = f2bf(x1.x); A.u[5] = f2bf(x1.y); A.u[6] = f2bf(x1.z); A.u[7] = f2bf(x1.w);
        #pragma unroll
        for (int nt = 0; nt < 4; ++nt) {
            bf16x8 bv = *(const bf16x8*)&WT[16 * nt + ml][kk + 8 * q];
            acc[nt] = __builtin_amdgcn_mfma_f32_16x16x32_bf16(A.v, bv, acc[nt], 0, 0, 0);
        }
    }

    // C layout: col(n)=16nt+ml, row(m)=i0+16w+4q+rr -> hT[n][m], 4 consecutive m => 8B store
    #pragma unroll
    for (int nt = 0; nt < 4; ++nt) {
        ushort4 o;
        o.x = f2bf(acc[nt][0]); o.y = f2bf(acc[nt][1]);
        o.z = f2bf(acc[nt][2]); o.w = f2bf(acc[nt][3]);
        *(ushort4*)&hT[(size_t)(16 * nt + ml) * N_NODES + i0 + 16 * wave + 4 * q] = o;
    }
}

// ---------------- kernel 2 (R2-proven): s_part[ks] = adj_slice @ h ; deg rowsum
__global__ __launch_bounds__(256) void k_spmm(const int* __restrict__ adj,
                                              const unsigned short* __restrict__ hT,
                                              float* __restrict__ s_part,
                                              int* __restrict__ deg_part) {
    // padded stride 72 (=8*9): keeps b128 alignment, rotates banks by 4/row
    __shared__ __align__(16) unsigned short As[64][72];   // adj tile as bf16 0/1
    __shared__ __align__(16) unsigned short Bs[64][72];   // Bs[n][k] = h[k][n]

    int tid  = threadIdx.x;
    int lane = tid & 63;
    int wave = tid >> 6;
    int q    = lane >> 4;       // quad 0..3
    int ml   = lane & 15;
    int i0   = blockIdx.x * MT;
    int ks   = blockIdx.y;
    int k0b  = ks * (N_NODES / KSPLIT);
    int r    = tid >> 2;        // staging row 0..63
    int cq   = (tid & 3) * 16;  // staging col chunk

    f32x4 acc[4];
    #pragma unroll
    for (int nt = 0; nt < 4; ++nt) acc[nt] = (f32x4){0.f, 0.f, 0.f, 0.f};
    int degacc = 0;

    const int iters = (N_NODES / KSPLIT) / BK;   // 48
    for (int it = 0; it < iters; ++it) {
        int k0 = k0b + it * BK;

        const int* ap = adj + (size_t)(i0 + r) * N_NODES + k0 + cq;
        int4 a0 = ((const int4*)ap)[0];
        int4 a1 = ((const int4*)ap)[1];
        int4 a2 = ((const int4*)ap)[2];
        int4 a3 = ((const int4*)ap)[3];

        const unsigned short* bp = hT + (size_t)r * N_NODES + k0 + cq;
        uint4 b01 = ((const uint4*)bp)[0];
        uint4 b23 = ((const uint4*)bp)[1];

        degacc += a0.x + a0.y + a0.z + a0.w;
        degacc += a1.x + a1.y + a1.z + a1.w;
        degacc += a2.x + a2.y + a2.z + a2.w;
        degacc += a3.x + a3.y + a3.z + a3.w;

        ushort4 c0, c1, c2, c3;
        c0.x = a0.x ? 0x3F80 : 0; c0.y = a0.y ? 0x3F80 : 0; c0.z = a0.z ? 0x3F80 : 0; c0.w = a0.w ? 0x3F80 : 0;
        c1.x = a1.x ? 0x3F80 : 0; c1.y = a1.y ? 0x3F80 : 0; c1.z = a1.z ? 0x3F80 : 0; c1.w = a1.w ? 0x3F80 : 0;
        c2.x = a2.x ? 0x3F80 : 0; c2.y = a2.y ? 0x3F80 : 0; c2.z = a2.z ? 0x3F80 : 0; c2.w = a2.w ? 0x3F80 : 0;
        c3.x = a3.x ? 0x3F80 : 0; c3.y = a3.y ? 0x3F80 : 0; c3.z = a3.z ? 0x3F80 : 0; c3.w = a3.w ? 0x3F80 : 0;

        *(ushort4*)&As[r][cq + 0]  = c0;
        *(ushort4*)&As[r][cq + 4]  = c1;
        *(ushort4*)&As[r][cq + 8]  = c2;
        *(ushort4*)&As[r][cq + 12] = c3;
        *(uint4*)&Bs[r][cq + 0] = b01;
        *(uint4*)&Bs[r][cq + 8] = b23;

        __syncthreads();

        #pragma unroll
        for (int kk = 0; kk < BK; kk += 32) {
            bf16x8 av = *(const bf16x8*)&As[16 * wave + ml][kk + 8 * q];
            #pragma unroll
            for (int nt = 0; nt < 4; ++nt) {
                bf16x8 bv = *(const bf16x8*)&Bs[16 * nt + ml][kk + 8 * q];
                acc[nt] = __builtin_amdgcn_mfma_f32_16x16x32_bf16(av, bv, acc[nt], 0, 0, 0);
            }
        }

        __syncthreads();
    }

    // epilogue: non-atomic partial store (each block owns its 64x64 region of slice ks)
    float* sp = s_part + (size_t)ks * ((size_t)N_NODES * OUT_F);
    #pragma unroll
    for (int nt = 0; nt < 4; ++nt) {
        #pragma unroll
        for (int rr = 0; rr < 4; ++rr) {
            int row = i0 + 16 * wave + 4 * q + rr;   // C layout: row = quad*4+reg
            int col = 16 * nt + ml;                  // col = lane&15
            sp[(size_t)row * OUT_F + col] = acc[nt][rr];
        }
    }

    degacc += __shfl_xor(degacc, 1, 64);
    degacc += __shfl_xor(degacc, 2, 64);
    if ((tid & 3) == 0)
        deg_part[ks * N_NODES + i0 + r] = degacc;
}

// ---------------- kernel 3: out = elu( sum_p s_part / sum_p deg_part ), fp32
__global__ __launch_bounds__(256) void k_out(const float* __restrict__ s_part,
                                             const int* __restrict__ deg_part,
                                             float* __restrict__ out) {
    int idx = blockIdx.x * 256 + threadIdx.x;
    int i = idx >> 6;
    float s = 0.f; int deg = 0;
    #pragma unroll
    for (int p = 0; p < KSPLIT; ++p) {
        s   += s_part[(size_t)p * ((size_t)N_NODES * OUT_F) + idx];
        deg += deg_part[p * N_NODES + i];
    }
    float v = (deg > 0) ? (s / (float)deg) : 0.f;
    out[idx] = (v > 0.f) ? v : expm1f(v);
}

extern "C" void kernel_launch(void* const* d_in, const int* in_sizes, int n_in,
                              void* d_out, int out_size, void* d_ws, size_t ws_size,
                              hipStream_t stream) {
    const int*   adj = (const int*)d_in[0];
    const float* x   = (const float*)d_in[1];   // fp32
    const float* W   = (const float*)d_in[2];   // fp32
    // d_in[3] (a) provably cancels out of the output — unused.
    float* out = (float*)d_out;                 // fp32

    char* ws = (char*)d_ws;
    const size_t hT_bytes = (size_t)N_NODES * OUT_F * 2;                 // 1.5 MB
    const size_t sp_bytes = (size_t)KSPLIT * N_NODES * OUT_F * 4;        // 12.6 MB
    unsigned short* hT = (unsigned short*)ws;
    float* s_part      = (float*)(ws + hT_bytes);
    int*   deg_part    = (int*)(ws + hT_bytes + sp_bytes);
    // total ~14.3 MB of d_ws

    k_hT  <<<dim3(N_NODES / MT),          dim3(256), 0, stream>>>(x, W, hT);
    k_spmm<<<dim3(N_NODES / MT, KSPLIT),  dim3(256), 0, stream>>>(adj, hT, s_part, deg_part);
    k_out <<<dim3(N_NODES * OUT_F / 256), dim3(256), 0, stream>>>(s_part, deg_part, out);
}